// Round 8
// baseline (542.941 us; speedup 1.0000x reference)
//
#include <hip/hip_runtime.h>

#define NN 100000
#define EE 1600000
#define NPAD 100032          // NN rounded up to 64-row MFMA tiles
#define NBKT 196             // ceil(NN/512) scatter buckets
#define CAP 9216             // bucket capacity (mean 8192, sigma 90 -> 11 sigma)
#define BN_EPS 1e-5f

using f32x4  = __attribute__((ext_vector_type(4))) float;
using s16x8  = __attribute__((ext_vector_type(8))) short;
using u16x4  = __attribute__((ext_vector_type(4))) unsigned short;
using bf16x8 = __attribute__((ext_vector_type(8))) __bf16;
typedef unsigned short ushort_t;

__device__ __forceinline__ float bf2f(ushort_t b) {
  union { unsigned u; float f; } x; x.u = ((unsigned)b) << 16; return x.f;
}
__device__ __forceinline__ ushort_t f2bf(float f) {
  union { float f; unsigned u; } x; x.f = f;
  unsigned r = x.u + 0x7fffu + ((x.u >> 16) & 1u);   // RN-even; no NaNs in pipeline
  return (ushort_t)(r >> 16);
}

// ---------------- CSR build: fixed-capacity two-level scatter ----------------
__global__ __launch_bounds__(256) void k_bin(const int* __restrict__ src,
                                             const int* __restrict__ dst,
                                             int* __restrict__ gbc,
                                             unsigned* __restrict__ ebuf) {
  __shared__ int hist[NBKT];
  int t = threadIdx.x;
  for (int i = t; i < NBKT; i += 256) hist[i] = 0;
  __syncthreads();
  int base = blockIdx.x * 4096;
  int s[16], d[16];
#pragma unroll
  for (int j = 0; j < 16; j++) {
    int e = base + j * 256 + t;
    if (e < EE) { s[j] = src[e]; d[j] = dst[e]; atomicAdd(&hist[d[j] >> 9], 1); }
    else d[j] = -1;
  }
  __syncthreads();
  for (int i = t; i < NBKT; i += 256) {
    int c = hist[i];
    hist[i] = c ? atomicAdd(&gbc[i], c) : 0;   // reserve in-bucket run
  }
  __syncthreads();
#pragma unroll
  for (int j = 0; j < 16; j++) {
    if (d[j] >= 0) {
      int bkt = d[j] >> 9;
      int pos = atomicAdd(&hist[bkt], 1);
      if (pos < CAP)                            // safety clamp (never hit here)
        ebuf[(size_t)bkt * CAP + pos] = (unsigned)s[j] | ((unsigned)(d[j] & 511) << 17);
    }
  }
}

// scan bucket counts -> ebase; rowptr[NN]=EE; zero BN stats
__global__ void k_bktscan(const int* __restrict__ gbc, int* __restrict__ ebase,
                          int* __restrict__ rowptr, float* __restrict__ stats) {
  __shared__ int sd[256];
  int t = threadIdx.x;
#pragma unroll
  for (int k = 0; k < 3; k++) stats[t + 256 * k] = 0.f;   // 768 floats
  int c = (t < NBKT) ? min(gbc[t], CAP) : 0;
  sd[t] = c; __syncthreads();
  for (int off = 1; off < 256; off <<= 1) {
    int x = 0;
    if (t >= off) x = sd[t - off];
    __syncthreads();
    sd[t] += x;
    __syncthreads();
  }
  if (t < NBKT) ebase[t] = sd[t] - c;          // exclusive
  if (t == NBKT - 1) rowptr[NN] = sd[t];       // == EE
}

// per bucket: LDS degree hist -> LDS scan -> rowptr + fine scatter (L2-resident window)
__global__ __launch_bounds__(256) void k_fine(const unsigned* __restrict__ ebuf,
                                              const int* __restrict__ gbc,
                                              const int* __restrict__ ebase,
                                              int* __restrict__ rowptr,
                                              int* __restrict__ csr) {
  __shared__ int dcur[512];
  __shared__ int sd[256];
  int b = blockIdx.x, t = threadIdx.x;
  int cnt = min(gbc[b], CAP);
  int eb = ebase[b];
  const unsigned* eb_p = ebuf + (size_t)b * CAP;
  dcur[t] = 0; dcur[t + 256] = 0;
  __syncthreads();
  for (int e = t; e < cnt; e += 256)
    atomicAdd(&dcur[(eb_p[e] >> 17) & 511], 1);
  __syncthreads();
  int a0 = dcur[2 * t], a1 = dcur[2 * t + 1];
  int ps = a0 + a1;
  sd[t] = ps; __syncthreads();
  for (int off = 1; off < 256; off <<= 1) {
    int x = 0;
    if (t >= off) x = sd[t - off];
    __syncthreads();
    sd[t] += x;
    __syncthreads();
  }
  int g0 = eb + sd[t] - ps;                    // global csr start for local node 2t
  dcur[2 * t] = g0; dcur[2 * t + 1] = g0 + a0;
  int n = (b << 9) + 2 * t;
  if (n < NN) rowptr[n] = g0;
  if (n + 1 < NN) rowptr[n + 1] = g0 + a0;
  __syncthreads();
  for (int e = t; e < cnt; e += 256) {
    unsigned v = eb_p[e];
    int pos = atomicAdd(&dcur[(v >> 17) & 511], 1);
    csr[pos] = (int)(v & 0x1FFFFu);
  }
}

// ---------------- misc prep ----------------
__global__ void k_x2b(const float* __restrict__ x, ushort_t* __restrict__ hb) {
  int i = blockIdx.x * 256 + threadIdx.x;   // each handles 4 elems
  f32x4 v = *(const f32x4*)(x + (size_t)i * 4);
  u16x4 o;
#pragma unroll
  for (int m = 0; m < 4; m++) o[m] = f2bf(v[m]);
  *(u16x4*)(hb + (size_t)i * 4) = o;
}

// Pre-swizzle fp32 W1/W2 into bf16 MFMA B-frag order.
// B[k][n]: n = t*16 + (lane&15), k = u*32 + (lane>>4)*8 + j.
__global__ void k_wprep(const float* __restrict__ W1s, const float* __restrict__ W2s,
                        ushort_t* __restrict__ wf) {
  int gid = blockIdx.x * blockDim.x + threadIdx.x;
  if (gid >= 3072) return;                  // 6 mats * 2u * 4t * 64 lanes
  int mat = gid >> 9, rem = gid & 511;
  int u = rem >> 8, t = (rem >> 6) & 3, lane = rem & 63;
  const float* W = ((mat & 1) ? W2s : W1s) + (mat >> 1) * 4096;
  ushort_t* o = wf + gid * 8;
#pragma unroll
  for (int j = 0; j < 8; j++) {
    int k = u * 32 + (lane >> 4) * 8 + j;
    int n = t * 16 + (lane & 15);
    o[j] = f2bf(W[k * 64 + n]);
  }
}

// ---------------- fused aggregate + mlp1 ----------------
// Phase 1 (round-6 gather structure): all 4 groups stride the SAME node's edge
// list (4 indep load instrs = 16 rows in flight per burst); wave walks its 16
// rows serially (work per wave ~ Poisson(256): balanced +-6%). Group-0-only LDS
// writes: conflict-free banks.
// Phase 2: MFMA z = s@W1 + b1 from LDS A-frags; BN sum/sumsq; z stored bf16.
__global__ __launch_bounds__(256) void k_aggmlp1(
    const ushort_t* __restrict__ hb, const int* __restrict__ rowptr,
    const int* __restrict__ csr, const ushort_t* __restrict__ wfrag,
    const float* __restrict__ b1, ushort_t* __restrict__ zb,
    float* __restrict__ stats) {
  __shared__ __align__(16) ushort_t sw[64 * 72];   // stride 72 elems (rows 16B-aligned)
  __shared__ float lsum[64], lsq[64];
  int tid = threadIdx.x;
  if (tid < 64) { lsum[tid] = 0.f; lsq[tid] = 0.f; }
  int wv = tid >> 6, lane = tid & 63;
  int g = lane >> 4, fl = lane & 15;
  const ushort_t* hbase = hb + fl * 4;

  // ---- phase 1: gather (16 nodes per wave, serial; 4 groups stride each) ----
  for (int i = 0; i < 16; i++) {
    int nl = wv * 16 + i;
    int node = blockIdx.x * 64 + nl;
    f32x4 a0 = {0,0,0,0};
    u16x4 selfr = {0,0,0,0};
    if (node < NN) {
      selfr = *(const u16x4*)(hbase + (size_t)node * 64);
      int beg = rowptr[node], end = rowptr[node + 1];
      f32x4 a1 = {0,0,0,0}, a2 = {0,0,0,0}, a3 = {0,0,0,0};
      int e = beg + g;
      for (; e + 12 < end; e += 16) {
        int s0 = csr[e], s1 = csr[e + 4], s2 = csr[e + 8], s3 = csr[e + 12];
        u16x4 r0 = *(const u16x4*)(hbase + (size_t)s0 * 64);
        u16x4 r1 = *(const u16x4*)(hbase + (size_t)s1 * 64);
        u16x4 r2 = *(const u16x4*)(hbase + (size_t)s2 * 64);
        u16x4 r3 = *(const u16x4*)(hbase + (size_t)s3 * 64);
#pragma unroll
        for (int m = 0; m < 4; m++) {
          a0[m] += bf2f(r0[m]); a1[m] += bf2f(r1[m]);
          a2[m] += bf2f(r2[m]); a3[m] += bf2f(r3[m]);
        }
      }
      for (; e < end; e += 4) {
        int s0 = csr[e];
        u16x4 r0 = *(const u16x4*)(hbase + (size_t)s0 * 64);
#pragma unroll
        for (int m = 0; m < 4; m++) a0[m] += bf2f(r0[m]);
      }
#pragma unroll
      for (int m = 0; m < 4; m++) a0[m] += a1[m] + a2[m] + a3[m];
    }
    // reduce across the 4 groups (lanes 16, 32 apart)
#pragma unroll
    for (int off = 16; off < 64; off <<= 1) {
#pragma unroll
      for (int m = 0; m < 4; m++) a0[m] += __shfl_xor(a0[m], off);
    }
    if (g == 0) {
      u16x4 o;
#pragma unroll
      for (int m = 0; m < 4; m++) o[m] = f2bf(a0[m] + bf2f(selfr[m]));
      *(u16x4*)(sw + nl * 72 + fl * 4) = o;   // 16 lanes, banks 0..31: conflict-free
    }
  }
  __syncthreads();

  // ---- phase 2: MFMA ----
  int quad = lane >> 4, lo = lane & 15;
  int row0 = blockIdx.x * 64 + wv * 16;
  s16x8 bfr[2][4];
#pragma unroll
  for (int u = 0; u < 2; u++)
#pragma unroll
    for (int t = 0; t < 4; t++)
      bfr[u][t] = *(const s16x8*)(wfrag + (size_t)((u * 4 + t) * 64 + lane) * 8);

  f32x4 acc[4] = {};
#pragma unroll
  for (int u = 0; u < 2; u++) {
    bf16x8 af = *(const bf16x8*)(sw + (wv * 16 + lo) * 72 + u * 32 + quad * 8);
#pragma unroll
    for (int t = 0; t < 4; t++)
      acc[t] = __builtin_amdgcn_mfma_f32_16x16x32_bf16(
          af, __builtin_bit_cast(bf16x8, bfr[u][t]), acc[t], 0, 0, 0);
  }
  // C/D layout: col = t*16 + lo, row = row0 + quad*4 + r
#pragma unroll
  for (int t = 0; t < 4; t++) {
    int col = t * 16 + lo;
    float bb = b1[col];
    float s1 = 0.f, s2 = 0.f;
#pragma unroll
    for (int r = 0; r < 4; r++) {
      int row = row0 + quad * 4 + r;
      if (row < NN) {
        float v = acc[t][r] + bb;
        zb[(size_t)row * 64 + col] = f2bf(v);
        s1 += v; s2 += v * v;
      }
    }
    atomicAdd(&lsum[col], s1);
    atomicAdd(&lsq[col], s2);
  }
  __syncthreads();
  if (tid < 64) {
    atomicAdd(&stats[tid], lsum[tid]);
    atomicAdd(&stats[64 + tid], lsq[tid]);
  }
}

// relu_out=1 (L0,L1): hb16 = relu( relu(zb*a+c)@W2 + b2 )
// relu_out=0 (L2):    h -> out+200000 (fp32) AND out[0..2N) = h@Wd + bd (fused decoder)
// BN finalize fused: each block computes a,c from raw sums (redundant, cheap).
__global__ __launch_bounds__(256) void k_mlp2(
    const ushort_t* __restrict__ zb, const float* __restrict__ stats,
    const float* __restrict__ gamma, const float* __restrict__ beta,
    const ushort_t* __restrict__ wfrag, const float* __restrict__ b2,
    ushort_t* __restrict__ hb, float* __restrict__ out,
    const float* __restrict__ Wd, const float* __restrict__ bd, int relu_out) {
  __shared__ __align__(16) ushort_t sw[64 * 72];
  __shared__ float abn[64], cbn[64];
  int tid = threadIdx.x;
  if (tid < 64) {   // fused BN finalize
    float inv = 1.f / (float)NN;
    float mu = stats[tid] * inv;
    float var = stats[64 + tid] * inv - mu * mu;
    float a = gamma[tid] * rsqrtf(var + BN_EPS);
    abn[tid] = a;
    cbn[tid] = beta[tid] - mu * a;
  }
  __syncthreads();
  {   // phase 1: BN affine + ReLU on bf16 z -> bf16 tile in LDS
    int r = tid >> 2, c0 = (tid & 3) * 16;
    size_t grow = (size_t)blockIdx.x * 64 + r;     // < NPAD; padded rows masked at store
#pragma unroll
    for (int jj = 0; jj < 16; jj += 8) {
      s16x8 zv = *(const s16x8*)(zb + grow * 64 + c0 + jj);
      f32x4 av0 = *(const f32x4*)(abn + c0 + jj);
      f32x4 av1 = *(const f32x4*)(abn + c0 + jj + 4);
      f32x4 cv0 = *(const f32x4*)(cbn + c0 + jj);
      f32x4 cv1 = *(const f32x4*)(cbn + c0 + jj + 4);
#pragma unroll
      for (int m = 0; m < 4; m++) {
        float v0 = fmaxf(bf2f((ushort_t)zv[m]) * av0[m] + cv0[m], 0.f);
        float v1 = fmaxf(bf2f((ushort_t)zv[m + 4]) * av1[m] + cv1[m], 0.f);
        sw[r * 72 + c0 + jj + m] = f2bf(v0);
        sw[r * 72 + c0 + jj + m + 4] = f2bf(v1);
      }
    }
  }
  __syncthreads();
  int wv = tid >> 6, lane = tid & 63;
  int quad = lane >> 4, lo = lane & 15;

  s16x8 bfr[2][4];
#pragma unroll
  for (int u = 0; u < 2; u++)
#pragma unroll
    for (int t = 0; t < 4; t++)
      bfr[u][t] = *(const s16x8*)(wfrag + (size_t)((u * 4 + t) * 64 + lane) * 8);

  f32x4 acc[4] = {};
#pragma unroll
  for (int u = 0; u < 2; u++) {
    bf16x8 af = *(const bf16x8*)(sw + (wv * 16 + lo) * 72 + u * 32 + quad * 8);
#pragma unroll
    for (int t = 0; t < 4; t++)
      acc[t] = __builtin_amdgcn_mfma_f32_16x16x32_bf16(
          af, __builtin_bit_cast(bf16x8, bfr[u][t]), acc[t], 0, 0, 0);
  }
  int row0 = blockIdx.x * 64 + wv * 16;
  float bbv[4];
#pragma unroll
  for (int t = 0; t < 4; t++) bbv[t] = b2[t * 16 + lo];

  if (relu_out) {
#pragma unroll
    for (int t = 0; t < 4; t++) {
      int col = t * 16 + lo;
#pragma unroll
      for (int r = 0; r < 4; r++) {
        int row = row0 + quad * 4 + r;
        if (row < NN)
          hb[(size_t)row * 64 + col] = f2bf(fmaxf(acc[t][r] + bbv[t], 0.f));
      }
    }
  } else {
    float* outh = out + (size_t)NN * 2;
    float wd0[4], wd1[4];
#pragma unroll
    for (int t = 0; t < 4; t++) {
      wd0[t] = Wd[(t * 16 + lo) * 2];
      wd1[t] = Wd[(t * 16 + lo) * 2 + 1];
    }
    float bd0 = bd[0], bd1 = bd[1];
#pragma unroll
    for (int t = 0; t < 4; t++) {
      int col = t * 16 + lo;
#pragma unroll
      for (int r = 0; r < 4; r++) {
        int row = row0 + quad * 4 + r;
        if (row < NN) outh[(size_t)row * 64 + col] = acc[t][r] + bbv[t];
      }
    }
#pragma unroll
    for (int r = 0; r < 4; r++) {
      float p0 = 0.f, p1 = 0.f;
#pragma unroll
      for (int t = 0; t < 4; t++) {
        float v = acc[t][r] + bbv[t];
        p0 += v * wd0[t]; p1 += v * wd1[t];
      }
#pragma unroll
      for (int o = 1; o < 16; o <<= 1) {   // reduce across the 16 lanes of the quad
        p0 += __shfl_xor(p0, o);
        p1 += __shfl_xor(p1, o);
      }
      int row = row0 + quad * 4 + r;
      if (lo == 0 && row < NN) {
        out[(size_t)row * 2 + 0] = p0 + bd0;
        out[(size_t)row * 2 + 1] = p1 + bd1;
      }
    }
  }
}

extern "C" void kernel_launch(void* const* d_in, const int* in_sizes, int n_in,
                              void* d_out, int out_size, void* d_ws, size_t ws_size,
                              hipStream_t stream) {
  (void)in_sizes; (void)n_in; (void)out_size; (void)ws_size;
  const float* x   = (const float*)d_in[0];
  const int*   ei  = (const int*)d_in[1];
  const float* W1s = (const float*)d_in[2];
  const float* b1s = (const float*)d_in[3];
  const float* gms = (const float*)d_in[4];
  const float* bts = (const float*)d_in[5];
  const float* W2s = (const float*)d_in[6];
  const float* b2s = (const float*)d_in[7];
  const float* Wd  = (const float*)d_in[8];
  const float* bd  = (const float*)d_in[9];
  float* out = (float*)d_out;
  const int* src = ei;
  const int* dst = ei + EE;

  char* w = (char*)d_ws;
  size_t off = 0;
  auto alloc = [&](size_t b) { char* p = w + off; off += (b + 255) & ~(size_t)255; return p; };
  ushort_t* zb     = (ushort_t*)alloc((size_t)NPAD * 64 * 2);   // 12.8 MB (ebuf aliases)
  ushort_t* hb16   = (ushort_t*)alloc((size_t)NPAD * 64 * 2);   // 12.8 MB bf16 rows
  int*      csr    = (int*)alloc((size_t)EE * 4);               // 6.4 MB
  int*      rowptr = (int*)alloc((size_t)(NN + 1) * 4);
  int*      gbc    = (int*)alloc((size_t)NBKT * 4);
  int*      ebase  = (int*)alloc((size_t)NBKT * 4);
  float*    stats  = (float*)alloc(768 * 4);                    // 3 x [sum|sq|spare]
  ushort_t* wf     = (ushort_t*)alloc((size_t)6 * 512 * 8 * 2); // swizzled W frags
  unsigned* ebuf   = (unsigned*)zb;  // 196*9216*4 = 7.2 MB, used pre-mlp only

  hipMemsetAsync(gbc, 0, (size_t)NBKT * 4, stream);
  k_bin    <<<(EE + 4095) / 4096, 256, 0, stream>>>(src, dst, gbc, ebuf);
  k_bktscan<<<1, 256, 0, stream>>>(gbc, ebase, rowptr, stats);
  k_fine   <<<NBKT, 256, 0, stream>>>(ebuf, gbc, ebase, rowptr, csr);
  k_x2b    <<<NN * 64 / 1024, 256, 0, stream>>>(x, hb16);
  k_wprep  <<<12, 256, 0, stream>>>(W1s, W2s, wf);

  for (int L = 0; L < 3; L++) {
    k_aggmlp1<<<(NN + 63) / 64, 256, 0, stream>>>(hb16, rowptr, csr,
                                                  wf + (size_t)(L * 2) * 4096,
                                                  b1s + L * 64, zb, stats + L * 256);
    k_mlp2<<<(NN + 63) / 64, 256, 0, stream>>>(zb, stats + L * 256,
                                               gms + L * 64, bts + L * 64,
                                               wf + (size_t)(L * 2 + 1) * 4096,
                                               b2s + L * 64, hb16, out, Wd, bd,
                                               (L < 2) ? 1 : 0);
  }
}

// Round 9
// 416.858 us; speedup vs baseline: 1.3025x; 1.3025x over previous
//
#include <hip/hip_runtime.h>

#define NN 100000
#define EE 1600000
#define NPAD 100032          // NN rounded up to 64-row MFMA tiles
#define NBKT 196             // ceil(NN/512) scatter buckets
#define CAP 9216             // bucket capacity (mean 8192, sigma 90 -> 11 sigma)
#define BN_EPS 1e-5f

using f32x4  = __attribute__((ext_vector_type(4))) float;
using f32x8  = __attribute__((ext_vector_type(8))) float;
using s16x8  = __attribute__((ext_vector_type(8))) short;
using u16x4  = __attribute__((ext_vector_type(4))) unsigned short;
using u16x8  = __attribute__((ext_vector_type(8))) unsigned short;
using bf16x8 = __attribute__((ext_vector_type(8))) __bf16;
typedef unsigned short ushort_t;

__device__ __forceinline__ float bf2f(ushort_t b) {
  union { unsigned u; float f; } x; x.u = ((unsigned)b) << 16; return x.f;
}
__device__ __forceinline__ ushort_t f2bf(float f) {
  union { float f; unsigned u; } x; x.f = f;
  unsigned r = x.u + 0x7fffu + ((x.u >> 16) & 1u);   // RN-even; no NaNs in pipeline
  return (ushort_t)(r >> 16);
}

// ---------------- CSR build: fixed-capacity two-level scatter ----------------
__global__ __launch_bounds__(256) void k_bin(const int* __restrict__ src,
                                             const int* __restrict__ dst,
                                             int* __restrict__ gbc,
                                             unsigned* __restrict__ ebuf) {
  __shared__ int hist[NBKT];
  int t = threadIdx.x;
  for (int i = t; i < NBKT; i += 256) hist[i] = 0;
  __syncthreads();
  int base = blockIdx.x * 4096;
  int s[16], d[16];
#pragma unroll
  for (int j = 0; j < 16; j++) {
    int e = base + j * 256 + t;
    if (e < EE) { s[j] = src[e]; d[j] = dst[e]; atomicAdd(&hist[d[j] >> 9], 1); }
    else d[j] = -1;
  }
  __syncthreads();
  for (int i = t; i < NBKT; i += 256) {
    int c = hist[i];
    hist[i] = c ? atomicAdd(&gbc[i], c) : 0;   // reserve in-bucket run
  }
  __syncthreads();
#pragma unroll
  for (int j = 0; j < 16; j++) {
    if (d[j] >= 0) {
      int bkt = d[j] >> 9;
      int pos = atomicAdd(&hist[bkt], 1);
      if (pos < CAP)                            // safety clamp (never hit here)
        ebuf[(size_t)bkt * CAP + pos] = (unsigned)s[j] | ((unsigned)(d[j] & 511) << 17);
    }
  }
}

// scan bucket counts -> ebase; rowptr[NN]=EE; zero BN stats
__global__ void k_bktscan(const int* __restrict__ gbc, int* __restrict__ ebase,
                          int* __restrict__ rowptr, float* __restrict__ stats) {
  __shared__ int sd[256];
  int t = threadIdx.x;
#pragma unroll
  for (int k = 0; k < 3; k++) stats[t + 256 * k] = 0.f;   // 768 floats
  int c = (t < NBKT) ? min(gbc[t], CAP) : 0;
  sd[t] = c; __syncthreads();
  for (int off = 1; off < 256; off <<= 1) {
    int x = 0;
    if (t >= off) x = sd[t - off];
    __syncthreads();
    sd[t] += x;
    __syncthreads();
  }
  if (t < NBKT) ebase[t] = sd[t] - c;          // exclusive
  if (t == NBKT - 1) rowptr[NN] = sd[t];       // == EE
}

// per bucket: LDS degree hist -> LDS scan -> rowptr + fine scatter (L2-resident window)
__global__ __launch_bounds__(256) void k_fine(const unsigned* __restrict__ ebuf,
                                              const int* __restrict__ gbc,
                                              const int* __restrict__ ebase,
                                              int* __restrict__ rowptr,
                                              int* __restrict__ csr) {
  __shared__ int dcur[512];
  __shared__ int sd[256];
  int b = blockIdx.x, t = threadIdx.x;
  int cnt = min(gbc[b], CAP);
  int eb = ebase[b];
  const unsigned* eb_p = ebuf + (size_t)b * CAP;
  dcur[t] = 0; dcur[t + 256] = 0;
  __syncthreads();
  for (int e = t; e < cnt; e += 256)
    atomicAdd(&dcur[(eb_p[e] >> 17) & 511], 1);
  __syncthreads();
  int a0 = dcur[2 * t], a1 = dcur[2 * t + 1];
  int ps = a0 + a1;
  sd[t] = ps; __syncthreads();
  for (int off = 1; off < 256; off <<= 1) {
    int x = 0;
    if (t >= off) x = sd[t - off];
    __syncthreads();
    sd[t] += x;
    __syncthreads();
  }
  int g0 = eb + sd[t] - ps;                    // global csr start for local node 2t
  dcur[2 * t] = g0; dcur[2 * t + 1] = g0 + a0;
  int n = (b << 9) + 2 * t;
  if (n < NN) rowptr[n] = g0;
  if (n + 1 < NN) rowptr[n + 1] = g0 + a0;
  __syncthreads();
  for (int e = t; e < cnt; e += 256) {
    unsigned v = eb_p[e];
    int pos = atomicAdd(&dcur[(v >> 17) & 511], 1);
    csr[pos] = (int)(v & 0x1FFFFu);
  }
}

// ---------------- merged prep: x->bf16 (blocks 0..6249) + W swizzle (6250..6261) ----
__global__ void k_prep(const float* __restrict__ x, ushort_t* __restrict__ hb,
                       const float* __restrict__ W1s, const float* __restrict__ W2s,
                       ushort_t* __restrict__ wf) {
  int b = blockIdx.x;
  if (b < 6250) {
    int i = b * 256 + threadIdx.x;   // each handles 4 elems of x
    f32x4 v = *(const f32x4*)(x + (size_t)i * 4);
    u16x4 o;
#pragma unroll
    for (int m = 0; m < 4; m++) o[m] = f2bf(v[m]);
    *(u16x4*)(hb + (size_t)i * 4) = o;
  } else {
    int gid = (b - 6250) * 256 + threadIdx.x;
    if (gid >= 3072) return;                  // 6 mats * 2u * 4t * 64 lanes
    int mat = gid >> 9, rem = gid & 511;
    int u = rem >> 8, t = (rem >> 6) & 3, lane = rem & 63;
    const float* W = ((mat & 1) ? W2s : W1s) + (mat >> 1) * 4096;
    ushort_t* o = wf + gid * 8;
#pragma unroll
    for (int j = 0; j < 8; j++) {
      int k = u * 32 + (lane >> 4) * 8 + j;
      int n = t * 16 + (lane & 15);
      o[j] = f2bf(W[k * 64 + n]);
    }
  }
}

// ---------------- fused aggregate + mlp1 ----------------
// 512 threads = 8 waves. Phase 1: 64 groups of 8 lanes; each group owns ONE node
// (no node serialization, no shuffles). Lane = 8 features (u16x8, 16B); x4 unroll
// -> 32 rows in flight per wave, 12504 gather waves. Rows -> LDS bf16.
// Phase 2 (waves 0-3): MFMA z = s@W1 + b1 from LDS; BN sum/sumsq; z stored bf16.
__global__ __launch_bounds__(512) void k_aggmlp1(
    const ushort_t* __restrict__ hb, const int* __restrict__ rowptr,
    const int* __restrict__ csr, const ushort_t* __restrict__ wfrag,
    const float* __restrict__ b1, ushort_t* __restrict__ zb,
    float* __restrict__ stats) {
  __shared__ __align__(16) ushort_t sw[64 * 72];   // stride 72 elems (rows 16B-aligned)
  __shared__ float lsum[64], lsq[64];
  int tid = threadIdx.x;
  if (tid < 64) { lsum[tid] = 0.f; lsq[tid] = 0.f; }
  int wv = tid >> 6, lane = tid & 63;
  int grp = lane >> 3, fl = lane & 7;
  int nl = wv * 8 + grp;                        // local node 0..63
  int node = blockIdx.x * 64 + nl;
  const ushort_t* hbase = hb + fl * 8;

  // ---- phase 1: gather (group owns node; private per-lane 8-feature sum) ----
  f32x8 a0 = {0,0,0,0,0,0,0,0};
  if (node < NN) {
    u16x8 selfr = *(const u16x8*)(hbase + (size_t)node * 64);
    int beg = rowptr[node], end = rowptr[node + 1];
    f32x8 a1 = a0, a2 = a0, a3 = a0;
    int e = beg;
    for (; e + 3 < end; e += 4) {
      int s0 = csr[e], s1 = csr[e + 1], s2 = csr[e + 2], s3 = csr[e + 3];
      u16x8 r0 = *(const u16x8*)(hbase + (size_t)s0 * 64);
      u16x8 r1 = *(const u16x8*)(hbase + (size_t)s1 * 64);
      u16x8 r2 = *(const u16x8*)(hbase + (size_t)s2 * 64);
      u16x8 r3 = *(const u16x8*)(hbase + (size_t)s3 * 64);
#pragma unroll
      for (int m = 0; m < 8; m++) {
        a0[m] += bf2f(r0[m]); a1[m] += bf2f(r1[m]);
        a2[m] += bf2f(r2[m]); a3[m] += bf2f(r3[m]);
      }
    }
    for (; e < end; e++) {
      int s0 = csr[e];
      u16x8 r0 = *(const u16x8*)(hbase + (size_t)s0 * 64);
#pragma unroll
      for (int m = 0; m < 8; m++) a0[m] += bf2f(r0[m]);
    }
#pragma unroll
    for (int m = 0; m < 8; m++) a0[m] += a1[m] + a2[m] + a3[m] + bf2f(selfr[m]);
  }
  {
    u16x8 o;
#pragma unroll
    for (int m = 0; m < 8; m++) o[m] = f2bf(a0[m]);
    *(u16x8*)(sw + nl * 72 + fl * 8) = o;
  }
  __syncthreads();

  // ---- phase 2: MFMA (waves 0-3 only; 16 rows each) ----
  if (wv < 4) {
    int quad = lane >> 4, lo = lane & 15;
    int row0 = blockIdx.x * 64 + wv * 16;
    s16x8 bfr[2][4];
#pragma unroll
    for (int u = 0; u < 2; u++)
#pragma unroll
      for (int t = 0; t < 4; t++)
        bfr[u][t] = *(const s16x8*)(wfrag + (size_t)((u * 4 + t) * 64 + lane) * 8);

    f32x4 acc[4] = {};
#pragma unroll
    for (int u = 0; u < 2; u++) {
      bf16x8 af = *(const bf16x8*)(sw + (wv * 16 + lo) * 72 + u * 32 + quad * 8);
#pragma unroll
      for (int t = 0; t < 4; t++)
        acc[t] = __builtin_amdgcn_mfma_f32_16x16x32_bf16(
            af, __builtin_bit_cast(bf16x8, bfr[u][t]), acc[t], 0, 0, 0);
    }
    // C/D layout: col = t*16 + lo, row = row0 + quad*4 + r
#pragma unroll
    for (int t = 0; t < 4; t++) {
      int col = t * 16 + lo;
      float bb = b1[col];
      float s1 = 0.f, s2 = 0.f;
#pragma unroll
      for (int r = 0; r < 4; r++) {
        int row = row0 + quad * 4 + r;
        if (row < NN) {
          float v = acc[t][r] + bb;
          zb[(size_t)row * 64 + col] = f2bf(v);
          s1 += v; s2 += v * v;
        }
      }
      atomicAdd(&lsum[col], s1);
      atomicAdd(&lsq[col], s2);
    }
  }
  __syncthreads();
  if (tid < 64) {
    atomicAdd(&stats[tid], lsum[tid]);
    atomicAdd(&stats[64 + tid], lsq[tid]);
  }
}

// relu_out=1 (L0,L1): hb16 = relu( relu(zb*a+c)@W2 + b2 )
// relu_out=0 (L2):    h -> out+200000 (fp32) AND out[0..2N) = h@Wd + bd (fused decoder)
// BN finalize fused: each block computes a,c from raw sums (redundant, cheap).
__global__ __launch_bounds__(256) void k_mlp2(
    const ushort_t* __restrict__ zb, const float* __restrict__ stats,
    const float* __restrict__ gamma, const float* __restrict__ beta,
    const ushort_t* __restrict__ wfrag, const float* __restrict__ b2,
    ushort_t* __restrict__ hb, float* __restrict__ out,
    const float* __restrict__ Wd, const float* __restrict__ bd, int relu_out) {
  __shared__ __align__(16) ushort_t sw[64 * 72];
  __shared__ float abn[64], cbn[64];
  int tid = threadIdx.x;
  if (tid < 64) {   // fused BN finalize
    float inv = 1.f / (float)NN;
    float mu = stats[tid] * inv;
    float var = stats[64 + tid] * inv - mu * mu;
    float a = gamma[tid] * rsqrtf(var + BN_EPS);
    abn[tid] = a;
    cbn[tid] = beta[tid] - mu * a;
  }
  __syncthreads();
  {   // phase 1: BN affine + ReLU on bf16 z -> bf16 tile in LDS
    int r = tid >> 2, c0 = (tid & 3) * 16;
    size_t grow = (size_t)blockIdx.x * 64 + r;     // < NPAD; padded rows masked at store
#pragma unroll
    for (int jj = 0; jj < 16; jj += 8) {
      s16x8 zv = *(const s16x8*)(zb + grow * 64 + c0 + jj);
      f32x4 av0 = *(const f32x4*)(abn + c0 + jj);
      f32x4 av1 = *(const f32x4*)(abn + c0 + jj + 4);
      f32x4 cv0 = *(const f32x4*)(cbn + c0 + jj);
      f32x4 cv1 = *(const f32x4*)(cbn + c0 + jj + 4);
#pragma unroll
      for (int m = 0; m < 4; m++) {
        float v0 = fmaxf(bf2f((ushort_t)zv[m]) * av0[m] + cv0[m], 0.f);
        float v1 = fmaxf(bf2f((ushort_t)zv[m + 4]) * av1[m] + cv1[m], 0.f);
        sw[r * 72 + c0 + jj + m] = f2bf(v0);
        sw[r * 72 + c0 + jj + m + 4] = f2bf(v1);
      }
    }
  }
  __syncthreads();
  int wv = tid >> 6, lane = tid & 63;
  int quad = lane >> 4, lo = lane & 15;

  s16x8 bfr[2][4];
#pragma unroll
  for (int u = 0; u < 2; u++)
#pragma unroll
    for (int t = 0; t < 4; t++)
      bfr[u][t] = *(const s16x8*)(wfrag + (size_t)((u * 4 + t) * 64 + lane) * 8);

  f32x4 acc[4] = {};
#pragma unroll
  for (int u = 0; u < 2; u++) {
    bf16x8 af = *(const bf16x8*)(sw + (wv * 16 + lo) * 72 + u * 32 + quad * 8);
#pragma unroll
    for (int t = 0; t < 4; t++)
      acc[t] = __builtin_amdgcn_mfma_f32_16x16x32_bf16(
          af, __builtin_bit_cast(bf16x8, bfr[u][t]), acc[t], 0, 0, 0);
  }
  int row0 = blockIdx.x * 64 + wv * 16;
  float bbv[4];
#pragma unroll
  for (int t = 0; t < 4; t++) bbv[t] = b2[t * 16 + lo];

  if (relu_out) {
#pragma unroll
    for (int t = 0; t < 4; t++) {
      int col = t * 16 + lo;
#pragma unroll
      for (int r = 0; r < 4; r++) {
        int row = row0 + quad * 4 + r;
        if (row < NN)
          hb[(size_t)row * 64 + col] = f2bf(fmaxf(acc[t][r] + bbv[t], 0.f));
      }
    }
  } else {
    float* outh = out + (size_t)NN * 2;
    float wd0[4], wd1[4];
#pragma unroll
    for (int t = 0; t < 4; t++) {
      wd0[t] = Wd[(t * 16 + lo) * 2];
      wd1[t] = Wd[(t * 16 + lo) * 2 + 1];
    }
    float bd0 = bd[0], bd1 = bd[1];
#pragma unroll
    for (int t = 0; t < 4; t++) {
      int col = t * 16 + lo;
#pragma unroll
      for (int r = 0; r < 4; r++) {
        int row = row0 + quad * 4 + r;
        if (row < NN) outh[(size_t)row * 64 + col] = acc[t][r] + bbv[t];
      }
    }
#pragma unroll
    for (int r = 0; r < 4; r++) {
      float p0 = 0.f, p1 = 0.f;
#pragma unroll
      for (int t = 0; t < 4; t++) {
        float v = acc[t][r] + bbv[t];
        p0 += v * wd0[t]; p1 += v * wd1[t];
      }
#pragma unroll
      for (int o = 1; o < 16; o <<= 1) {   // reduce across the 16 lanes of the quad
        p0 += __shfl_xor(p0, o);
        p1 += __shfl_xor(p1, o);
      }
      int row = row0 + quad * 4 + r;
      if (lo == 0 && row < NN) {
        out[(size_t)row * 2 + 0] = p0 + bd0;
        out[(size_t)row * 2 + 1] = p1 + bd1;
      }
    }
  }
}

extern "C" void kernel_launch(void* const* d_in, const int* in_sizes, int n_in,
                              void* d_out, int out_size, void* d_ws, size_t ws_size,
                              hipStream_t stream) {
  (void)in_sizes; (void)n_in; (void)out_size; (void)ws_size;
  const float* x   = (const float*)d_in[0];
  const int*   ei  = (const int*)d_in[1];
  const float* W1s = (const float*)d_in[2];
  const float* b1s = (const float*)d_in[3];
  const float* gms = (const float*)d_in[4];
  const float* bts = (const float*)d_in[5];
  const float* W2s = (const float*)d_in[6];
  const float* b2s = (const float*)d_in[7];
  const float* Wd  = (const float*)d_in[8];
  const float* bd  = (const float*)d_in[9];
  float* out = (float*)d_out;
  const int* src = ei;
  const int* dst = ei + EE;

  char* w = (char*)d_ws;
  size_t off = 0;
  auto alloc = [&](size_t b) { char* p = w + off; off += (b + 255) & ~(size_t)255; return p; };
  ushort_t* zb     = (ushort_t*)alloc((size_t)NPAD * 64 * 2);   // 12.8 MB (ebuf aliases)
  ushort_t* hb16   = (ushort_t*)alloc((size_t)NPAD * 64 * 2);   // 12.8 MB bf16 rows
  int*      csr    = (int*)alloc((size_t)EE * 4);               // 6.4 MB
  int*      rowptr = (int*)alloc((size_t)(NN + 1) * 4);
  int*      gbc    = (int*)alloc((size_t)NBKT * 4);
  int*      ebase  = (int*)alloc((size_t)NBKT * 4);
  float*    stats  = (float*)alloc(768 * 4);                    // 3 x [sum|sq|spare]
  ushort_t* wf     = (ushort_t*)alloc((size_t)6 * 512 * 8 * 2); // swizzled W frags
  unsigned* ebuf   = (unsigned*)zb;  // 196*9216*4 = 7.2 MB, used pre-mlp only

  hipMemsetAsync(gbc, 0, (size_t)NBKT * 4, stream);
  k_bin    <<<(EE + 4095) / 4096, 256, 0, stream>>>(src, dst, gbc, ebuf);
  k_bktscan<<<1, 256, 0, stream>>>(gbc, ebase, rowptr, stats);
  k_fine   <<<NBKT, 256, 0, stream>>>(ebuf, gbc, ebase, rowptr, csr);
  k_prep   <<<6262, 256, 0, stream>>>(x, hb16, W1s, W2s, wf);

  for (int L = 0; L < 3; L++) {
    k_aggmlp1<<<(NN + 63) / 64, 512, 0, stream>>>(hb16, rowptr, csr,
                                                  wf + (size_t)(L * 2) * 4096,
                                                  b1s + L * 64, zb, stats + L * 256);
    k_mlp2<<<(NN + 63) / 64, 256, 0, stream>>>(zb, stats + L * 256,
                                               gms + L * 64, bts + L * 64,
                                               wf + (size_t)(L * 2 + 1) * 4096,
                                               b2s + L * 64, hb16, out, Wd, bd,
                                               (L < 2) ? 1 : 0);
  }
}